// Round 4
// baseline (249.915 us; speedup 1.0000x reference)
//
#include <hip/hip_runtime.h>
#include <hip/hip_bf16.h>

// Problem constants
#define B_   2
#define N_   512
#define M_   512
#define D_   128    // Dq = Dk = Dv
#define DE_  64
#define H_   8
#define O_   32
#define OUT_ 128
#define DKE_ 192    // Dk + De
#define MP_  516    // padded M for attn_s rows

typedef unsigned short u16;
typedef unsigned int   u32;
typedef short bf16x8 __attribute__((ext_vector_type(8)));
typedef float floatx4 __attribute__((ext_vector_type(4)));

__device__ __forceinline__ u32 pk2bf(float a, float b) {
    __hip_bfloat162 h = __float22bfloat162_rn(make_float2(a, b));
    return *reinterpret_cast<u32*>(&h);
}
__device__ __forceinline__ u16 f2bf(float a) {
    __hip_bfloat16 h = __float2bfloat16(a);
    return *reinterpret_cast<u16*>(&h);
}
// pack 8 fp32 (two float4) -> bf16x8 fragment
__device__ __forceinline__ bf16x8 cvt8(const float4 a, const float4 b) {
    union { u32 u[4]; bf16x8 v; } r;
    r.u[0] = pk2bf(a.x, a.y); r.u[1] = pk2bf(a.z, a.w);
    r.u[2] = pk2bf(b.x, b.y); r.u[3] = pk2bf(b.z, b.w);
    return r.v;
}

// ---------------------------------------------------------------------------
// k_proj, grid = 320 x 256 threads.
// Blocks 0..127   : per 8 (b,n) rows -> qE bf16 [row][h*192+j]  (q.Wq/sqrt, fold Wk)
// Blocks 128..255 : per 8 (b,m) rows -> vP bf16 [b][m>>3][col=h*32+o][m&7]
// Blocks 256..319 : keyF: key in bf16 MFMA-B-fragment order
//                   keyF[b][tl][kk][lane][8], lane=(q<<4)|br,
//                   element j = key[b][tl*16+br][kk*32+q*8+j]
// ---------------------------------------------------------------------------
__global__ __launch_bounds__(256) void k_proj(
    const float* __restrict__ query, const float* __restrict__ Wq,
    const float* __restrict__ Wk,
    const float* __restrict__ value, const float* __restrict__ Wv,
    const float* __restrict__ key,
    u16* __restrict__ qE, u16* __restrict__ vP, u16* __restrict__ keyF)
{
    const int t = threadIdx.x;
    __shared__ float Xs[8][D_];
    __shared__ float qh[8][H_ * O_];

    if (blockIdx.x < 128) {
        const int r0 = blockIdx.x * 8;
        reinterpret_cast<float4*>(&Xs[0][0])[t] =
            reinterpret_cast<const float4*>(query + (size_t)r0 * D_)[t];
        __syncthreads();
        {
            float acc[8] = {0,0,0,0,0,0,0,0};
            const float* wcol = Wq + (t >> 5) * (D_ * O_) + (t & 31);
            for (int k = 0; k < D_; k += 4) {
                const float w0 = wcol[(k+0) * O_];
                const float w1 = wcol[(k+1) * O_];
                const float w2 = wcol[(k+2) * O_];
                const float w3 = wcol[(k+3) * O_];
#pragma unroll
                for (int r = 0; r < 8; ++r) {
                    const float4 x = *reinterpret_cast<const float4*>(&Xs[r][k]);
                    acc[r] += x.x * w0 + x.y * w1 + x.z * w2 + x.w * w3;
                }
            }
#pragma unroll
            for (int r = 0; r < 8; ++r) qh[r][t] = acc[r] * 0.17677669529663687f;
        }
        __syncthreads();

        for (int s = 0; s < 6; ++s) {
            const int hj = t + 256 * s;
            const int h  = hj / DKE_;
            float w[O_];
#pragma unroll
            for (int i = 0; i < O_ / 4; ++i) {
                const float4 x = reinterpret_cast<const float4*>(Wk + (size_t)hj * O_)[i];
                w[4*i] = x.x; w[4*i+1] = x.y; w[4*i+2] = x.z; w[4*i+3] = x.w;
            }
#pragma unroll
            for (int r = 0; r < 8; ++r) {
                const float* qrow = &qh[r][h * O_];
                float a = 0.f;
#pragma unroll
                for (int i = 0; i < O_ / 4; ++i) {
                    const float4 qx = *reinterpret_cast<const float4*>(qrow + 4*i);
                    a += qx.x * w[4*i] + qx.y * w[4*i+1] + qx.z * w[4*i+2] + qx.w * w[4*i+3];
                }
                qE[(size_t)(r0 + r) * (H_ * DKE_) + hj] = f2bf(a);
            }
        }
    } else if (blockIdx.x < 256) {
        const int r0 = (blockIdx.x - 128) * 8;          // global (b,m) row
        reinterpret_cast<float4*>(&Xs[0][0])[t] =
            reinterpret_cast<const float4*>(value + (size_t)r0 * D_)[t];
        __syncthreads();

        float acc[8] = {0,0,0,0,0,0,0,0};
        const float* wcol = Wv + (t >> 5) * (D_ * O_) + (t & 31);
        for (int k = 0; k < D_; k += 4) {
            const float w0 = wcol[(k+0) * O_];
            const float w1 = wcol[(k+1) * O_];
            const float w2 = wcol[(k+2) * O_];
            const float w3 = wcol[(k+3) * O_];
#pragma unroll
            for (int r = 0; r < 8; ++r) {
                const float4 x = *reinterpret_cast<const float4*>(&Xs[r][k]);
                acc[r] += x.x * w0 + x.y * w1 + x.z * w2 + x.w * w3;
            }
        }
        // PV-coalesced bf16 write: vP[b][m0>>3][col=t][0..7] as one 16 B store
        const int bb = r0 >> 9, m0 = r0 & 511;
        union { u32 u[4]; uint4 q; } pk;
        pk.u[0] = pk2bf(acc[0], acc[1]);
        pk.u[1] = pk2bf(acc[2], acc[3]);
        pk.u[2] = pk2bf(acc[4], acc[5]);
        pk.u[3] = pk2bf(acc[6], acc[7]);
        *reinterpret_cast<uint4*>(
            vP + ((((size_t)bb * 64) + (m0 >> 3)) * 256 + t) * 8) = pk.q;
    } else {
        // keyF builder: one block per (b, m-tile)
        const int kb = blockIdx.x - 256;                // 0..63
        const int bb = kb >> 5, tl = kb & 31;
        const int kk = t >> 6, l = t & 63;
        const int br = l & 15, q = l >> 4;
        const float* src = key + ((size_t)bb * M_ + tl * 16 + br) * D_ + kk * 32 + q * 8;
        const float4 f0 = *reinterpret_cast<const float4*>(src);
        const float4 f1 = *reinterpret_cast<const float4*>(src + 4);
        union { bf16x8 v; uint4 u; } r;
        r.v = cvt8(f0, f1);
        *reinterpret_cast<uint4*>(
            keyF + ((((size_t)bb * 32 + tl) * 4 + kk) * 64 + l) * 8) = r.u;
    }
}

// ---------------------------------------------------------------------------
// k_attn: one block per (b,n), 256 threads = 4 waves, LDS 26.75 KB ->
// up to 6 blocks/CU co-resident in DIFFERENT phases (logits-HBM of one block
// overlaps PV-L2/softmax/MLP of others). No prologue: qE precomputed.
// Edge staging: permuted-coalesced global float4 loads (16 full lines/instr)
// -> byte-linear LDS writes (zero conflicts) -> granule-linear b128 fragment
// reads (zero conflicts). Key B-fragments coalesced from keyF.
// ---------------------------------------------------------------------------
__global__ __launch_bounds__(256, 6) void k_attn(
    const float* __restrict__ edge,
    const u16* __restrict__ qE, const u16* __restrict__ vP,
    const u16* __restrict__ keyF,
    const float* __restrict__ Wp, const float* __restrict__ bias,
    float* __restrict__ out)
{
    const int idx  = blockIdx.x;          // b*N + n
    const int b    = idx >> 9;
    const int t    = threadIdx.x;
    const int lane = t & 63;
    const int wv   = t >> 6;              // 0..3

    __shared__ __attribute__((aligned(16))) float attn_s[H_][MP_]; // 16.5 KB
    __shared__ __attribute__((aligned(16))) u16 elds[4][1024];     // 8 KB
    __shared__ float mh_s[H_ * O_];                                // 1 KB
    __shared__ float part_s[2][OUT_];                              // 1 KB

    const int br = lane & 15;             // A row (head) / C col (m)
    const int q  = lane >> 4;             // k-quad

    // lane->chunk permutation for edge loads (float4 units within a tile):
    // instruction covers rows 0-15 x one 64B column block = 16 full lines;
    // LDS dest = i*512 + lane*8 bytes (byte-linear -> zero-conflict writes).
    const int base16 = ((lane >> 1) & 15) * 16 + ((lane >> 5) << 1) + (lane & 1);

    // ---- early edge prefetch: first tile for this wave (tl = wv) ----
    const float4* tb = reinterpret_cast<const float4*>(edge + (size_t)idx * (M_ * DE_));
    float4 ef[4];
#pragma unroll
    for (int i = 0; i < 4; ++i)
        ef[i] = tb[wv * 256 + base16 + i * 4];

    // ---- A fragments: lane holds qE[row=br][kk*32 + q*8 + 0..7], rows>=8 zero
    bf16x8 afr[6];
    if (br < 8) {
        const u16* ab = qE + (size_t)idx * (H_ * DKE_) + br * DKE_;
#pragma unroll
        for (int kk = 0; kk < 6; ++kk)
            afr[kk] = *reinterpret_cast<const bf16x8*>(ab + kk * 32 + q * 8);
    } else {
#pragma unroll
        for (int kk = 0; kk < 6; ++kk) afr[kk] = bf16x8{0,0,0,0,0,0,0,0};
    }

    const u16* kfb = keyF + (size_t)b * (32 * 4 * 64 * 8);

    // ---- logits: 8 m-tiles per wave, no barriers inside ----
    for (int it = 0; it < 8; ++it) {
        const int tl = it * 4 + wv;
        // stage current tile: byte-linear LDS writes (zero conflicts)
#pragma unroll
        for (int i = 0; i < 4; ++i) {
            uint2 p;
            p.x = pk2bf(ef[i].x, ef[i].y); p.y = pk2bf(ef[i].z, ef[i].w);
            *reinterpret_cast<uint2*>(&elds[wv][i * 256 + lane * 4]) = p;
        }
        // prefetch next tile (same permuted-coalesced pattern)
        if (it < 7) {
#pragma unroll
            for (int i = 0; i < 4; ++i)
                ef[i] = tb[(tl + 4) * 256 + base16 + i * 4];
        }
        // key MFMAs: coalesced fragment loads from keyF
        floatx4 acc = {0.f, 0.f, 0.f, 0.f};
        const u16* kf = kfb + (size_t)tl * 2048 + lane * 8;
#pragma unroll
        for (int kk = 0; kk < 4; ++kk) {
            const bf16x8 bfr = *reinterpret_cast<const bf16x8*>(kf + kk * 512);
            acc = __builtin_amdgcn_mfma_f32_16x16x32_bf16(afr[kk], bfr, acc, 0, 0, 0);
        }
        // edge MFMAs: granule-linear b128 reads (zero conflicts)
#pragma unroll
        for (int kk = 0; kk < 2; ++kk) {
            const bf16x8 bfr = *reinterpret_cast<const bf16x8*>(&elds[wv][(kk * 64 + lane) * 8]);
            acc = __builtin_amdgcn_mfma_f32_16x16x32_bf16(afr[4 + kk], bfr, acc, 0, 0, 0);
        }
        // C: col=br (m), row=q*4+i = head; only rows 0..7 valid
        if (q < 2) {
#pragma unroll
            for (int i = 0; i < 4; ++i)
                attn_s[q * 4 + i][tl * 16 + br] = acc[i];
        }
    }
    __syncthreads();

    // ---- softmax over m per head (32 lanes own one head row) ----
    {
        const int h = t >> 5, ml = t & 31;
        float mx = -3.4e38f;
#pragma unroll 2
        for (int j = 0; j < 16; ++j) mx = fmaxf(mx, attn_s[h][ml + 32 * j]);
#pragma unroll
        for (int mask = 16; mask >= 1; mask >>= 1) mx = fmaxf(mx, __shfl_xor(mx, mask, 64));
        float sum = 0.f;
#pragma unroll 2
        for (int j = 0; j < 16; ++j) {
            const int m = ml + 32 * j;
            const float p = __expf(attn_s[h][m] - mx);
            attn_s[h][m] = p;
            sum += p;
        }
#pragma unroll
        for (int mask = 16; mask >= 1; mask >>= 1) sum += __shfl_xor(sum, mask, 64);
        const float inv = 1.f / sum;
#pragma unroll 2
        for (int j = 0; j < 16; ++j) attn_s[h][ml + 32 * j] *= inv;
    }
    __syncthreads();

    // ---- PV: thread t = col (h,o); coalesced uint4 stream from vP ----
    {
        const int hh = t >> 5;
        const u16* vb = vP + (size_t)b * (64 * 256 * 8) + (size_t)t * 8;
        float a0 = 0.f, a1 = 0.f;
#pragma unroll 8
        for (int j = 0; j < 64; ++j) {
            const uint4 v4 = *reinterpret_cast<const uint4*>(vb + (size_t)j * 2048);
            const float4 w0 = *reinterpret_cast<const float4*>(&attn_s[hh][j * 8]);
            const float4 w1 = *reinterpret_cast<const float4*>(&attn_s[hh][j * 8 + 4]);
            const float v0 = __uint_as_float(v4.x << 16);
            const float v1 = __uint_as_float(v4.x & 0xffff0000u);
            const float v2 = __uint_as_float(v4.y << 16);
            const float v3 = __uint_as_float(v4.y & 0xffff0000u);
            const float v4f = __uint_as_float(v4.z << 16);
            const float v5 = __uint_as_float(v4.z & 0xffff0000u);
            const float v6 = __uint_as_float(v4.w << 16);
            const float v7 = __uint_as_float(v4.w & 0xffff0000u);
            a0 += w0.x * v0 + w0.y * v1 + w0.z * v2 + w0.w * v3;
            a1 += w1.x * v4f + w1.y * v5 + w1.z * v6 + w1.w * v7;
        }
        mh_s[t] = a0 + a1;
    }
    __syncthreads();

    // ---- out[c] = bias[c] + sum_j mh[j] * Wp[j*128 + c] ----
    {
        const int half = t >> 7;
        const int c = t & 127;
        float acc = 0.f;
        const int j0 = half * 128;
#pragma unroll 8
        for (int jj = 0; jj < 128; ++jj)
            acc += mh_s[j0 + jj] * Wp[(size_t)(j0 + jj) * OUT_ + c];
        part_s[half][c] = acc;
    }
    __syncthreads();
    if (t < OUT_)
        out[(size_t)idx * OUT_ + t] = part_s[0][t] + part_s[1][t] + bias[t];
}

// ---------------------------------------------------------------------------
extern "C" void kernel_launch(void* const* d_in, const int* in_sizes, int n_in,
                              void* d_out, int out_size, void* d_ws, size_t ws_size,
                              hipStream_t stream)
{
    const float* query = (const float*)d_in[0];   // [B,N,128]
    const float* key   = (const float*)d_in[1];   // [B,M,128]
    const float* value = (const float*)d_in[2];   // [B,M,128]
    const float* edge  = (const float*)d_in[3];   // [B,N,M,64]
    const float* Wq    = (const float*)d_in[4];   // [8,128,32]
    const float* Wk    = (const float*)d_in[5];   // [8,192,32]
    const float* Wv    = (const float*)d_in[6];   // [8,128,32]
    const float* Wp    = (const float*)d_in[7];   // [8,32,128]
    const float* bias  = (const float*)d_in[8];   // [128]
    float* out = (float*)d_out;                   // [B,N,128] fp32

    u16* qE_ws = (u16*)d_ws;                                  // 1024*1536*2 = 3.1 MB
    u16* vP_ws = qE_ws + (size_t)B_ * N_ * H_ * DKE_;         // 2*64*256*8*2 = 512 KB
    u16* kF_ws = vP_ws + (size_t)B_ * 64 * 256 * 8;           // 2*32*4*64*8*2 = 256 KB

    k_proj<<<320,  256, 0, stream>>>(query, Wq, Wk, value, Wv, key, qE_ws, vP_ws, kF_ws);
    k_attn<<<1024, 256, 0, stream>>>(edge, qE_ws, vP_ws, kF_ws, Wp, bias, out);
}

// Round 5
// 241.900 us; speedup vs baseline: 1.0331x; 1.0331x over previous
//
#include <hip/hip_runtime.h>
#include <hip/hip_bf16.h>

// Problem constants
#define B_   2
#define N_   512
#define M_   512
#define D_   128    // Dq = Dk = Dv
#define DE_  64
#define H_   8
#define O_   32
#define OUT_ 128
#define DKE_ 192    // Dk + De
#define MP_  516    // padded M for attn_s rows

typedef unsigned short u16;
typedef unsigned int   u32;
typedef short bf16x8 __attribute__((ext_vector_type(8)));
typedef float floatx4 __attribute__((ext_vector_type(4)));

__device__ __forceinline__ u32 pk2bf(float a, float b) {
    __hip_bfloat162 h = __float22bfloat162_rn(make_float2(a, b));
    return *reinterpret_cast<u32*>(&h);
}
__device__ __forceinline__ u16 f2bf(float a) {
    __hip_bfloat16 h = __float2bfloat16(a);
    return *reinterpret_cast<u16*>(&h);
}
// pack 8 fp32 (two float4) -> bf16x8 fragment
__device__ __forceinline__ bf16x8 cvt8(const float4 a, const float4 b) {
    union { u32 u[4]; bf16x8 v; } r;
    r.u[0] = pk2bf(a.x, a.y); r.u[1] = pk2bf(a.z, a.w);
    r.u[2] = pk2bf(b.x, b.y); r.u[3] = pk2bf(b.z, b.w);
    return r.v;
}

// ---------------------------------------------------------------------------
// k_proj, grid = 320 x 256 threads.
// Blocks 0..127   : per 8 (b,n) rows -> qE bf16 [row][h*192+j]  (q.Wq/sqrt, fold Wk)
// Blocks 128..255 : per 8 (b,m) rows -> vP bf16 [b][m>>3][col=h*32+o][m&7]
// Blocks 256..319 : keyF: key in bf16 MFMA-B-fragment order
//                   keyF[b][tl][kk][lane][8], lane=(q<<4)|br,
//                   element j = key[b][tl*16+br][kk*32+q*8+j]
// ---------------------------------------------------------------------------
__global__ __launch_bounds__(256) void k_proj(
    const float* __restrict__ query, const float* __restrict__ Wq,
    const float* __restrict__ Wk,
    const float* __restrict__ value, const float* __restrict__ Wv,
    const float* __restrict__ key,
    u16* __restrict__ qE, u16* __restrict__ vP, u16* __restrict__ keyF)
{
    const int t = threadIdx.x;
    __shared__ float Xs[8][D_];
    __shared__ float qh[8][H_ * O_];

    if (blockIdx.x < 128) {
        const int r0 = blockIdx.x * 8;
        reinterpret_cast<float4*>(&Xs[0][0])[t] =
            reinterpret_cast<const float4*>(query + (size_t)r0 * D_)[t];
        __syncthreads();
        {
            float acc[8] = {0,0,0,0,0,0,0,0};
            const float* wcol = Wq + (t >> 5) * (D_ * O_) + (t & 31);
            for (int k = 0; k < D_; k += 4) {
                const float w0 = wcol[(k+0) * O_];
                const float w1 = wcol[(k+1) * O_];
                const float w2 = wcol[(k+2) * O_];
                const float w3 = wcol[(k+3) * O_];
#pragma unroll
                for (int r = 0; r < 8; ++r) {
                    const float4 x = *reinterpret_cast<const float4*>(&Xs[r][k]);
                    acc[r] += x.x * w0 + x.y * w1 + x.z * w2 + x.w * w3;
                }
            }
#pragma unroll
            for (int r = 0; r < 8; ++r) qh[r][t] = acc[r] * 0.17677669529663687f;
        }
        __syncthreads();

        for (int s = 0; s < 6; ++s) {
            const int hj = t + 256 * s;
            const int h  = hj / DKE_;
            float w[O_];
#pragma unroll
            for (int i = 0; i < O_ / 4; ++i) {
                const float4 x = reinterpret_cast<const float4*>(Wk + (size_t)hj * O_)[i];
                w[4*i] = x.x; w[4*i+1] = x.y; w[4*i+2] = x.z; w[4*i+3] = x.w;
            }
#pragma unroll
            for (int r = 0; r < 8; ++r) {
                const float* qrow = &qh[r][h * O_];
                float a = 0.f;
#pragma unroll
                for (int i = 0; i < O_ / 4; ++i) {
                    const float4 qx = *reinterpret_cast<const float4*>(qrow + 4*i);
                    a += qx.x * w[4*i] + qx.y * w[4*i+1] + qx.z * w[4*i+2] + qx.w * w[4*i+3];
                }
                qE[(size_t)(r0 + r) * (H_ * DKE_) + hj] = f2bf(a);
            }
        }
    } else if (blockIdx.x < 256) {
        const int r0 = (blockIdx.x - 128) * 8;          // global (b,m) row
        reinterpret_cast<float4*>(&Xs[0][0])[t] =
            reinterpret_cast<const float4*>(value + (size_t)r0 * D_)[t];
        __syncthreads();

        float acc[8] = {0,0,0,0,0,0,0,0};
        const float* wcol = Wv + (t >> 5) * (D_ * O_) + (t & 31);
        for (int k = 0; k < D_; k += 4) {
            const float w0 = wcol[(k+0) * O_];
            const float w1 = wcol[(k+1) * O_];
            const float w2 = wcol[(k+2) * O_];
            const float w3 = wcol[(k+3) * O_];
#pragma unroll
            for (int r = 0; r < 8; ++r) {
                const float4 x = *reinterpret_cast<const float4*>(&Xs[r][k]);
                acc[r] += x.x * w0 + x.y * w1 + x.z * w2 + x.w * w3;
            }
        }
        // PV-coalesced bf16 write: vP[b][m0>>3][col=t][0..7] as one 16 B store
        const int bb = r0 >> 9, m0 = r0 & 511;
        union { u32 u[4]; uint4 q; } pk;
        pk.u[0] = pk2bf(acc[0], acc[1]);
        pk.u[1] = pk2bf(acc[2], acc[3]);
        pk.u[2] = pk2bf(acc[4], acc[5]);
        pk.u[3] = pk2bf(acc[6], acc[7]);
        *reinterpret_cast<uint4*>(
            vP + ((((size_t)bb * 64) + (m0 >> 3)) * 256 + t) * 8) = pk.q;
    } else {
        // keyF builder: one block per (b, m-tile)
        const int kb = blockIdx.x - 256;                // 0..63
        const int bb = kb >> 5, tl = kb & 31;
        const int kk = t >> 6, l = t & 63;
        const int br = l & 15, q = l >> 4;
        const float* src = key + ((size_t)bb * M_ + tl * 16 + br) * D_ + kk * 32 + q * 8;
        const float4 f0 = *reinterpret_cast<const float4*>(src);
        const float4 f1 = *reinterpret_cast<const float4*>(src + 4);
        union { bf16x8 v; uint4 u; } r;
        r.v = cvt8(f0, f1);
        *reinterpret_cast<uint4*>(
            keyF + ((((size_t)bb * 32 + tl) * 4 + kk) * 64 + l) * 8) = r.u;
    }
}

// ---------------------------------------------------------------------------
// k_attn: one block per (b,n), 512 threads = 8 waves, LDS 36.5 KB ->
// 4 blocks/CU co-resident = 32 waves/CU (full slot capacity; grid is exactly
// 4 blocks/CU so this doubles TLP vs the 256-thread variant). All phases use
// all 8 waves: logits 4 m-tiles/wave, softmax 1 head/wave, PV m-halves,
// MLP 4 j-segments. Edge staging: permuted-coalesced global float4 loads
// (16 full lines/instr) -> byte-linear LDS writes (zero conflicts) ->
// granule-linear b128 fragment reads (zero conflicts).
// ---------------------------------------------------------------------------
__global__ __launch_bounds__(512, 8) void k_attn(
    const float* __restrict__ edge,
    const u16* __restrict__ qE, const u16* __restrict__ vP,
    const u16* __restrict__ keyF,
    const float* __restrict__ Wp, const float* __restrict__ bias,
    float* __restrict__ out)
{
    const int idx  = blockIdx.x;          // b*N + n
    const int b    = idx >> 9;
    const int t    = threadIdx.x;
    const int lane = t & 63;
    const int wv   = t >> 6;              // 0..7

    __shared__ __attribute__((aligned(16))) float attn_s[H_][MP_]; // 16.5 KB
    __shared__ __attribute__((aligned(16))) u16 elds[8][1024];     // 16 KB
    __shared__ float mh_s[2][256];                                 // 2 KB
    __shared__ float part_s[4][OUT_];                              // 2 KB

    const int br = lane & 15;             // A row (head) / C col (m)
    const int q  = lane >> 4;             // k-quad

    // lane->chunk permutation for edge loads (float4 units within a tile):
    // instruction covers rows 0-15 x one 64B column block = 16 full lines;
    // LDS dest = i*512 + lane*8 bytes (byte-linear -> zero-conflict writes).
    const int base16 = ((lane >> 1) & 15) * 16 + ((lane >> 5) << 1) + (lane & 1);

    // ---- early edge prefetch: first tile for this wave (tl = wv) ----
    const float4* tb = reinterpret_cast<const float4*>(edge + (size_t)idx * (M_ * DE_));
    float4 ef[4];
#pragma unroll
    for (int i = 0; i < 4; ++i)
        ef[i] = tb[wv * 256 + base16 + i * 4];

    // ---- A fragments: lane holds qE[row=br][kk*32 + q*8 + 0..7], rows>=8 zero
    bf16x8 afr[6];
    if (br < 8) {
        const u16* ab = qE + (size_t)idx * (H_ * DKE_) + br * DKE_;
#pragma unroll
        for (int kk = 0; kk < 6; ++kk)
            afr[kk] = *reinterpret_cast<const bf16x8*>(ab + kk * 32 + q * 8);
    } else {
#pragma unroll
        for (int kk = 0; kk < 6; ++kk) afr[kk] = bf16x8{0,0,0,0,0,0,0,0};
    }

    const u16* kfb = keyF + (size_t)b * (32 * 4 * 64 * 8);

    // ---- logits: 4 m-tiles per wave, no barriers inside ----
    for (int it = 0; it < 4; ++it) {
        const int tl = it * 8 + wv;
        // stage current tile: byte-linear LDS writes (zero conflicts)
#pragma unroll
        for (int i = 0; i < 4; ++i) {
            uint2 p;
            p.x = pk2bf(ef[i].x, ef[i].y); p.y = pk2bf(ef[i].z, ef[i].w);
            *reinterpret_cast<uint2*>(&elds[wv][i * 256 + lane * 4]) = p;
        }
        // prefetch next tile (same permuted-coalesced pattern)
        if (it < 3) {
#pragma unroll
            for (int i = 0; i < 4; ++i)
                ef[i] = tb[(tl + 8) * 256 + base16 + i * 4];
        }
        // key MFMAs: coalesced fragment loads from keyF
        floatx4 acc = {0.f, 0.f, 0.f, 0.f};
        const u16* kf = kfb + (size_t)tl * 2048 + lane * 8;
#pragma unroll
        for (int kk = 0; kk < 4; ++kk) {
            const bf16x8 bfr = *reinterpret_cast<const bf16x8*>(kf + kk * 512);
            acc = __builtin_amdgcn_mfma_f32_16x16x32_bf16(afr[kk], bfr, acc, 0, 0, 0);
        }
        // edge MFMAs: granule-linear b128 reads (zero conflicts)
#pragma unroll
        for (int kk = 0; kk < 2; ++kk) {
            const bf16x8 bfr = *reinterpret_cast<const bf16x8*>(&elds[wv][(kk * 64 + lane) * 8]);
            acc = __builtin_amdgcn_mfma_f32_16x16x32_bf16(afr[4 + kk], bfr, acc, 0, 0, 0);
        }
        // C: col=br (m), row=q*4+i = head; only rows 0..7 valid
        if (q < 2) {
#pragma unroll
            for (int i = 0; i < 4; ++i)
                attn_s[q * 4 + i][tl * 16 + br] = acc[i];
        }
    }
    __syncthreads();

    // ---- softmax over m: wave wv owns head wv; 64 lanes x 8 elems ----
    {
        const int h = wv, ml = lane;
        float mx = -3.4e38f;
#pragma unroll
        for (int j = 0; j < 8; ++j) mx = fmaxf(mx, attn_s[h][ml + 64 * j]);
#pragma unroll
        for (int mask = 32; mask >= 1; mask >>= 1) mx = fmaxf(mx, __shfl_xor(mx, mask, 64));
        float sum = 0.f;
#pragma unroll
        for (int j = 0; j < 8; ++j) {
            const int m = ml + 64 * j;
            const float p = __expf(attn_s[h][m] - mx);
            attn_s[h][m] = p;
            sum += p;
        }
#pragma unroll
        for (int mask = 32; mask >= 1; mask >>= 1) sum += __shfl_xor(sum, mask, 64);
        const float inv = 1.f / sum;
#pragma unroll
        for (int j = 0; j < 8; ++j) attn_s[h][ml + 64 * j] *= inv;
    }
    __syncthreads();

    // ---- PV: col tt=(h,o), m in halves; coalesced uint4 stream from vP ----
    {
        const int tt = t & 255, half = t >> 8, hh = tt >> 5;
        const u16* vb = vP + (size_t)b * (64 * 256 * 8)
                      + ((size_t)(half * 32) * 256 + tt) * 8;
        const int mbase = half * 256;
        float a0 = 0.f, a1 = 0.f;
#pragma unroll 8
        for (int j = 0; j < 32; ++j) {
            const uint4 v4 = *reinterpret_cast<const uint4*>(vb + (size_t)j * 2048);
            const int m0 = mbase + j * 8;
            const float4 w0 = *reinterpret_cast<const float4*>(&attn_s[hh][m0]);
            const float4 w1 = *reinterpret_cast<const float4*>(&attn_s[hh][m0 + 4]);
            const float v0 = __uint_as_float(v4.x << 16);
            const float v1 = __uint_as_float(v4.x & 0xffff0000u);
            const float v2 = __uint_as_float(v4.y << 16);
            const float v3 = __uint_as_float(v4.y & 0xffff0000u);
            const float v4f = __uint_as_float(v4.z << 16);
            const float v5 = __uint_as_float(v4.z & 0xffff0000u);
            const float v6 = __uint_as_float(v4.w << 16);
            const float v7 = __uint_as_float(v4.w & 0xffff0000u);
            a0 += w0.x * v0 + w0.y * v1 + w0.z * v2 + w0.w * v3;
            a1 += w1.x * v4f + w1.y * v5 + w1.z * v6 + w1.w * v7;
        }
        mh_s[half][tt] = a0 + a1;
    }
    __syncthreads();

    // ---- out[c] = bias[c] + sum_j mh[j] * Wp[j*128 + c], 4 j-segments ----
    {
        const int seg = t >> 7, c = t & 127;
        const int j0 = seg * 64;
        float acc = 0.f;
#pragma unroll 8
        for (int jj = 0; jj < 64; ++jj) {
            const int j = j0 + jj;
            acc += (mh_s[0][j] + mh_s[1][j]) * Wp[(size_t)j * OUT_ + c];
        }
        part_s[seg][c] = acc;
    }
    __syncthreads();
    if (t < OUT_)
        out[(size_t)idx * OUT_ + t] = part_s[0][t] + part_s[1][t]
                                    + part_s[2][t] + part_s[3][t] + bias[t];
}

// ---------------------------------------------------------------------------
extern "C" void kernel_launch(void* const* d_in, const int* in_sizes, int n_in,
                              void* d_out, int out_size, void* d_ws, size_t ws_size,
                              hipStream_t stream)
{
    const float* query = (const float*)d_in[0];   // [B,N,128]
    const float* key   = (const float*)d_in[1];   // [B,M,128]
    const float* value = (const float*)d_in[2];   // [B,M,128]
    const float* edge  = (const float*)d_in[3];   // [B,N,M,64]
    const float* Wq    = (const float*)d_in[4];   // [8,128,32]
    const float* Wk    = (const float*)d_in[5];   // [8,192,32]
    const float* Wv    = (const float*)d_in[6];   // [8,128,32]
    const float* Wp    = (const float*)d_in[7];   // [8,32,128]
    const float* bias  = (const float*)d_in[8];   // [128]
    float* out = (float*)d_out;                   // [B,N,128] fp32

    u16* qE_ws = (u16*)d_ws;                                  // 1024*1536*2 = 3.1 MB
    u16* vP_ws = qE_ws + (size_t)B_ * N_ * H_ * DKE_;         // 2*64*256*8*2 = 512 KB
    u16* kF_ws = vP_ws + (size_t)B_ * 64 * 256 * 8;           // 2*32*4*64*8*2 = 256 KB

    k_proj<<<320,  256, 0, stream>>>(query, Wq, Wk, value, Wv, key, qE_ws, vP_ws, kF_ws);
    k_attn<<<1024, 512, 0, stream>>>(edge, qE_ws, vP_ws, kF_ws, Wp, bias, out);
}